// Round 10
// baseline (285.498 us; speedup 1.0000x reference)
//
#include <hip/hip_runtime.h>
#include <hip/hip_fp16.h>

// GraphSAGE 3-layer + head, MI355X.
// R9 -> R10 (aggs are VALU-bound at 63% busy; cut issued ops per edge):
//   - srcs indices loaded as aligned int4 (broadcast): 16 loads -> 4 per batch.
//     Aligned-16 edge blocks + wave-uniform masks (SALU cmp/cselect; masked
//     contribution = v_fmac with SGPR mask). srcs padded +16 zeros.
//   - 32-bit byte offsets ((idx<<8)+lane*4) from uniform base -> saddr-form
//     global_load, 1 VALU per address instead of 64-bit math.
// Gather laws: one row per vmem instruction (R7); >=16 independent loads in
// flight (R8); never funnel atomics into few cache lines (R5).

typedef __attribute__((ext_vector_type(8))) short bf16x8;
typedef __attribute__((ext_vector_type(4))) float f32x4;

struct Seg { const unsigned short* A; const unsigned short* W; int lda; int ldw; int K; };
struct Segs { Seg s[4]; int n; };

__device__ __forceinline__ unsigned short f2bf(float x) {
  unsigned u = __float_as_uint(x);
  u += 0x7FFF + ((u >> 16) & 1);   // RNE
  return (unsigned short)(u >> 16);
}
__device__ __forceinline__ unsigned short f2h(float x) {
  return __half_as_ushort(__float2half(x));
}
__device__ __forceinline__ float2 h2f2(unsigned u) {
  __half2 h = *reinterpret_cast<__half2*>(&u);
  return __half22float2(h);
}
__device__ __forceinline__ float2 ld_h2(const unsigned short* p, size_t idx) {
  return h2f2(*(const unsigned*)(p + idx));
}

// ---------------- CSR build: multi-block radix partition ----------------
__global__ __launch_bounds__(256) void hist_k(const int* __restrict__ tgt, int* __restrict__ histT,
                                              int E, int NB, int CH) {
  extern __shared__ int sh[];
  int g = blockIdx.x, tid = threadIdx.x;
  for (int b = tid; b < NB; b += 256) sh[b] = 0;
  __syncthreads();
  int eb = g * CH, ee = min(eb + CH, E);
  for (int i = eb + tid; i < ee; i += 256)
    atomicAdd(&sh[tgt[i] >> 6], 1);
  __syncthreads();
  for (int b = tid; b < NB; b += 256) histT[b * 64 + g] = sh[b];
}

__global__ __launch_bounds__(256) void scanb_k(int* __restrict__ histT, int* __restrict__ bcnt, int NB) {
  int wv = threadIdx.x >> 6, lane = threadIdx.x & 63;
  int b = blockIdx.x * 4 + wv;
  if (b >= NB) return;
  int v = histT[b * 64 + lane];
  int x = v;
#pragma unroll
  for (int o = 1; o < 64; o <<= 1) {
    int y = __shfl_up(x, o);
    if (lane >= o) x += y;
  }
  histT[b * 64 + lane] = x - v;
  if (lane == 63) bcnt[b] = x;
}

__global__ __launch_bounds__(1024) void bscan_k(const int* __restrict__ bcnt, int* __restrict__ boff,
                                                int* __restrict__ row_ptr, int* __restrict__ srcs,
                                                int NB, int E, int N) {
  __shared__ int sh[1024];
  int tid = threadIdx.x;
  int v = (tid < NB) ? bcnt[tid] : 0;
  int val = v;
  sh[tid] = val;
  __syncthreads();
  for (int o = 1; o < 1024; o <<= 1) {
    int t = (tid >= o) ? sh[tid - o] : 0;
    __syncthreads();
    val += t;
    sh[tid] = val;
    __syncthreads();
  }
  if (tid < NB) boff[tid] = val - v;
  if (tid == NB - 1) boff[NB] = val;
  if (tid == 0) row_ptr[N] = E;
  if (tid < 16) srcs[E + tid] = 0;   // pad: aligned-block gather may read past E
}

__global__ __launch_bounds__(256) void scatter_k(const int* __restrict__ src, const int* __restrict__ tgt,
                                                 const int* __restrict__ boff, const int* __restrict__ histT,
                                                 unsigned* __restrict__ vals, int E, int NB, int CH) {
  extern __shared__ int sh[];
  int g = blockIdx.x, tid = threadIdx.x;
  for (int b = tid; b < NB; b += 256) sh[b] = boff[b] + histT[b * 64 + g];
  __syncthreads();
  int eb = g * CH, ee = min(eb + CH, E);
  for (int i = eb + tid; i < ee; i += 256) {
    int t = tgt[i], s = src[i];
    int pos = atomicAdd(&sh[t >> 6], 1);
    vals[pos] = (unsigned)s | ((unsigned)(t & 63) << 17);
  }
}

// ---------------- merged: per-bucket sort + prep (conv/packs/head fold) ----------------
__global__ __launch_bounds__(256) void bsort_prep_k(
    const unsigned* __restrict__ vals, const int* __restrict__ boff,
    int* __restrict__ row_ptr, int* __restrict__ srcs, int N, int NB,
    const float* __restrict__ x, unsigned short* __restrict__ xb, int nbConv, int n4,
    const float* __restrict__ Wf_l, const float* __restrict__ Wf_r, unsigned short* __restrict__ Wt1hi,
    const float* __restrict__ W0_l, const float* __restrict__ W0_r, unsigned short* __restrict__ Wt2hi,
    const float* __restrict__ W1_l, const float* __restrict__ W1_r, unsigned short* __restrict__ Wt3hi,
    const float* __restrict__ Wlin, const float* __restrict__ blin,
    const float* __restrict__ Wlin2, const float* __restrict__ blin2,
    float* __restrict__ Wc, float* __restrict__ bc) {
  int b = blockIdx.x, tid = threadIdx.x;
  if (b < NB) {                      // ---- bsort part ----
    int base = b << 6;
    int s0 = boff[b], s1 = boff[b + 1];
    __shared__ int hist[64], excl[64], cur[64];
    if (tid < 64) { hist[tid] = 0; cur[tid] = 0; }
    __syncthreads();
    for (int i = s0 + tid; i < s1; i += 256)
      atomicAdd(&hist[(vals[i] >> 17) & 63], 1);
    __syncthreads();
    if (tid < 64) {
      int v = hist[tid];
      int xx = v;
#pragma unroll
      for (int o = 1; o < 64; o <<= 1) {
        int y = __shfl_up(xx, o);
        if (tid >= o) xx += y;
      }
      excl[tid] = xx - v;
      int node = base + tid;
      if (node < N) row_ptr[node] = s0 + xx - v;
    }
    __syncthreads();
    for (int i = s0 + tid; i < s1; i += 256) {
      unsigned v = vals[i];
      int l = (v >> 17) & 63;
      int pos = s0 + excl[l] + atomicAdd(&cur[l], 1);
      srcs[pos] = (int)(v & 0x1FFFF);
    }
    return;
  }
  b -= NB;                           // ---- prep part ----
  if (b < nbConv) {
    int i = b * 256 + tid;
    if (i < n4) {
      float4 v = ((const float4*)x)[i];
      ((ushort2*)xb)[i * 2]     = make_ushort2(f2bf(v.x), f2bf(v.y));
      ((ushort2*)xb)[i * 2 + 1] = make_ushort2(f2bf(v.z), f2bf(v.w));
    }
    return;
  }
  b -= nbConv;
  if (b < 128) {             // L1 k-split pack, hi only: Wt1[n][k] (256 x 128)
    int idx = b * 256 + tid;
    int n = idx >> 7, k = idx & 127;
    float v = (k < 64) ? Wf_l[k * 256 + n] : Wf_r[(k - 64) * 256 + n];
    Wt1hi[idx] = f2bf(v);
    return;
  }
  b -= 128;
  if (b < 256) {             // L2 n-split pack: Wt2[n][k] (256 x 256)
    int idx = b * 256 + tid;
    int n = idx >> 8, k = idx & 255;
    float v = (n < 128) ? W0_l[k * 128 + n] : W0_r[k * 128 + (n - 128)];
    Wt2hi[idx] = f2bf(v);
    return;
  }
  b -= 256;
  if (b < 128) {             // L3 n-split pack: Wt3[n][k] (256 x 128)
    int idx = b * 256 + tid;
    int n = idx >> 7, k = idx & 127;
    float v = (n < 128) ? W1_l[k * 128 + n] : W1_r[k * 128 + (n - 128)];
    Wt3hi[idx] = f2bf(v);
    return;
  }
  b -= 128;
  {                          // head fold: 4 blocks
    int idx = b * 256 + tid;
    if (idx < 1024) {
      int i = idx >> 3, j = idx & 7;
      float acc = 0.f;
      for (int k = 0; k < 128; ++k) acc = fmaf(Wlin[i * 128 + k], Wlin2[k * 8 + j], acc);
      Wc[idx] = acc;
    }
    if (idx < 8) {
      float acc = blin2[idx];
      for (int k = 0; k < 128; ++k) acc = fmaf(blin[k], Wlin2[k * 8 + idx], acc);
      bc[idx] = acc;
    }
  }
}

// ---------------- aggregation ----------------
// wave per node, D=64, lane=dim, fp32 gather from x (256B rows).
// Aligned-16 edge blocks; int4 srcs broadcast loads; 32-bit saddr offsets;
// wave-uniform masks (SALU).
__global__ __launch_bounds__(256) void agg_mean64_k(const float* __restrict__ x, const int* __restrict__ rp,
                                                    const int* __restrict__ srcs, unsigned short* __restrict__ mb, int n) {
  int w = threadIdx.x >> 6, lane = threadIdx.x & 63;
  int node = blockIdx.x * 4 + w;
  if (node >= n) return;
  int s0 = __builtin_amdgcn_readfirstlane(rp[node]);
  int s1 = __builtin_amdgcn_readfirstlane(rp[node + 1]);
  const unsigned char* xB = (const unsigned char*)x;
  unsigned db = (unsigned)lane * 4u;
  float sum = 0.f;
  for (int b = s0 & ~15; b < s1; b += 16) {
    int4 q0 = *(const int4*)&srcs[b];
    int4 q1 = *(const int4*)&srcs[b + 4];
    int4 q2 = *(const int4*)&srcs[b + 8];
    int4 q3 = *(const int4*)&srcs[b + 12];
    int idx[16] = {q0.x, q0.y, q0.z, q0.w, q1.x, q1.y, q1.z, q1.w,
                   q2.x, q2.y, q2.z, q2.w, q3.x, q3.y, q3.z, q3.w};
    float v[16];
#pragma unroll
    for (int i = 0; i < 16; ++i)
      v[i] = *(const float*)(xB + (((unsigned)idx[i] << 8) + db));
#pragma unroll
    for (int i = 0; i < 16; ++i) {
      float m = (b + i >= s0 && b + i < s1) ? 1.f : 0.f;   // uniform -> SALU
      sum = fmaf(m, v[i], sum);
    }
  }
  int deg = s1 - s0;
  float inv = 1.f / (float)(deg > 0 ? deg : 1);
  mb[(size_t)node * 64 + lane] = f2bf(sum * inv);
}

// wave per node, D=128, lane = 2 dims, fp16 gather (256B rows).
// OUTMODE 1: hout = bf16 h (N x 128). OUTMODE 2: fused head -> out fp32 (N x 8).
template <int OUTMODE>
__global__ __launch_bounds__(256) void agg128_k(const unsigned short* __restrict__ yb,
                                                const unsigned short* __restrict__ zb,
                                                const float* __restrict__ bias,
                                                const int* __restrict__ rp, const int* __restrict__ srcs,
                                                void* __restrict__ hout,
                                                const float* __restrict__ Wc, const float* __restrict__ bc, int n) {
  int w = threadIdx.x >> 6, lane = threadIdx.x & 63;
  int node = blockIdx.x * 4 + w;
  if (node >= n) return;
  int s0 = __builtin_amdgcn_readfirstlane(rp[node]);
  int s1 = __builtin_amdgcn_readfirstlane(rp[node + 1]);
  const unsigned char* ybB = (const unsigned char*)yb;
  unsigned db = (unsigned)lane * 4u;
  int d = lane * 2;
  float sx = 0.f, sy = 0.f;
  for (int b = s0 & ~15; b < s1; b += 16) {
    int4 q0 = *(const int4*)&srcs[b];
    int4 q1 = *(const int4*)&srcs[b + 4];
    int4 q2 = *(const int4*)&srcs[b + 8];
    int4 q3 = *(const int4*)&srcs[b + 12];
    int idx[16] = {q0.x, q0.y, q0.z, q0.w, q1.x, q1.y, q1.z, q1.w,
                   q2.x, q2.y, q2.z, q2.w, q3.x, q3.y, q3.z, q3.w};
    unsigned uv[16];
#pragma unroll
    for (int i = 0; i < 16; ++i)
      uv[i] = *(const unsigned*)(ybB + (((unsigned)idx[i] << 8) + db));
#pragma unroll
    for (int i = 0; i < 16; ++i) {
      float m = (b + i >= s0 && b + i < s1) ? 1.f : 0.f;   // uniform -> SALU
      float2 v = h2f2(uv[i]);
      sx = fmaf(m, v.x, sx);
      sy = fmaf(m, v.y, sy);
    }
  }
  int deg = s1 - s0;
  float inv = 1.f / (float)(deg > 0 ? deg : 1);
  float2 z = ld_h2(zb, (size_t)node * 128 + d);
  float2 b2 = *(const float2*)&bias[d];
  float ox = fmaxf(fmaf(sx, inv, z.x + b2.x), 0.f);
  float oy = fmaxf(fmaf(sy, inv, z.y + b2.y), 0.f);

  if (OUTMODE == 1) {
    ((ushort2*)hout)[((size_t)node * 128 + d) / 2] = make_ushort2(f2bf(ox), f2bf(oy));
  } else {
    // fused head: out[node][j] = sum_d o_d * Wc[d][j] + bc[j]
    const float4* wr = (const float4*)&Wc[d * 8];
    float4 wa0 = wr[0], wa1 = wr[1], wb0 = wr[2], wb1 = wr[3];
    float a8[8];
    a8[0] = ox * wa0.x + oy * wb0.x;
    a8[1] = ox * wa0.y + oy * wb0.y;
    a8[2] = ox * wa0.z + oy * wb0.z;
    a8[3] = ox * wa0.w + oy * wb0.w;
    a8[4] = ox * wa1.x + oy * wb1.x;
    a8[5] = ox * wa1.y + oy * wb1.y;
    a8[6] = ox * wa1.z + oy * wb1.z;
    a8[7] = ox * wa1.w + oy * wb1.w;
#pragma unroll
    for (int off = 32; off >= 1; off >>= 1) {
#pragma unroll
      for (int j = 0; j < 8; ++j) a8[j] += __shfl_xor(a8[j], off);
    }
    if (lane == 0) {
      float* o = (float*)hout + (size_t)node * 8;
      *(float4*)o       = make_float4(a8[0] + bc[0], a8[1] + bc[1], a8[2] + bc[2], a8[3] + bc[3]);
      *(float4*)(o + 4) = make_float4(a8[4] + bc[4], a8[5] + bc[5], a8[6] + bc[6], a8[7] + bc[7]);
    }
  }
}

// ---------------- MFMA GEMM ----------------
// Block tile 128x128, 4 waves (2x2), each wave 64x64 via 4x4 frags of 16x16x32 bf16 MFMA.
// MODE 0: fp16 out, split into Y (cols 0..127) / Z (cols 128..255), ld 128.
// MODE 1: bias+relu -> bf16 out Ob (ldc 256).
template <int MODE>
__global__ __launch_bounds__(256) void gemm_mfma_k(Segs segs, const float* __restrict__ bias,
                                                   unsigned short* __restrict__ Y, unsigned short* __restrict__ Z,
                                                   unsigned short* __restrict__ Ob, int ldc) {
  __shared__ unsigned short Asl[128 * 32];
  __shared__ unsigned short Wsl[128 * 32];
  int tid = threadIdx.x;
  int lane = tid & 63, wave = tid >> 6;
  int wm = wave & 1, wn = wave >> 1;
  int rowBase = blockIdx.x * 128, colBase = blockIdx.y * 128;
  f32x4 acc[4][4] = {};

  int c0 = tid, c1 = tid + 256;
  int r0 = c0 >> 2, q0 = c0 & 3;
  int r1 = c1 >> 2, q1 = c1 & 3;
  int ml = lane & 15, qq = lane >> 4;

  for (int si = 0; si < segs.n; ++si) {
    const unsigned short* Aseg = segs.s[si].A;
    const unsigned short* Wseg = segs.s[si].W;
    int lda = segs.s[si].lda, ldw = segs.s[si].ldw, K = segs.s[si].K;
    for (int k0 = 0; k0 < K; k0 += 32) {
      uint4 av0 = *(const uint4*)&Aseg[(size_t)(rowBase + r0) * lda + k0 + q0 * 8];
      uint4 av1 = *(const uint4*)&Aseg[(size_t)(rowBase + r1) * lda + k0 + q1 * 8];
      uint4 wv0 = *(const uint4*)&Wseg[(size_t)(colBase + r0) * ldw + k0 + q0 * 8];
      uint4 wv1 = *(const uint4*)&Wseg[(size_t)(colBase + r1) * ldw + k0 + q1 * 8];
      __syncthreads();
      *(uint4*)&Asl[c0 * 8] = av0;
      *(uint4*)&Asl[c1 * 8] = av1;
      *(uint4*)&Wsl[c0 * 8] = wv0;
      *(uint4*)&Wsl[c1 * 8] = wv1;
      __syncthreads();
      bf16x8 af[4], bw[4];
#pragma unroll
      for (int i = 0; i < 4; ++i) {
        af[i] = *(bf16x8*)&Asl[(wm * 64 + i * 16 + ml) * 32 + qq * 8];
        bw[i] = *(bf16x8*)&Wsl[(wn * 64 + i * 16 + ml) * 32 + qq * 8];
      }
#pragma unroll
      for (int mf = 0; mf < 4; ++mf)
#pragma unroll
        for (int nf = 0; nf < 4; ++nf)
          acc[mf][nf] = __builtin_amdgcn_mfma_f32_16x16x32_bf16(af[mf], bw[nf], acc[mf][nf], 0, 0, 0);
    }
  }

  if (MODE == 0) {
    unsigned short* dst = (colBase == 0) ? Y : Z;
#pragma unroll
    for (int mf = 0; mf < 4; ++mf) {
      int row = rowBase + wm * 64 + mf * 16 + qq * 4;
#pragma unroll
      for (int nf = 0; nf < 4; ++nf) {
        int col = wn * 64 + nf * 16 + ml;
#pragma unroll
        for (int r = 0; r < 4; ++r)
          dst[(size_t)(row + r) * 128 + col] = f2h(acc[mf][nf][r]);
      }
    }
  } else {
    float bc4[4];
#pragma unroll
    for (int nf = 0; nf < 4; ++nf) bc4[nf] = bias[colBase + wn * 64 + nf * 16 + ml];
#pragma unroll
    for (int mf = 0; mf < 4; ++mf) {
      int row = rowBase + wm * 64 + mf * 16 + qq * 4;
#pragma unroll
      for (int nf = 0; nf < 4; ++nf) {
        int col = colBase + wn * 64 + nf * 16 + ml;
#pragma unroll
        for (int r = 0; r < 4; ++r) {
          float o = fmaxf(acc[mf][nf][r] + bc4[nf], 0.f);
          Ob[(size_t)(row + r) * ldc + col] = f2bf(o);
        }
      }
    }
  }
}

// ---------------- host ----------------
extern "C" void kernel_launch(void* const* d_in, const int* in_sizes, int n_in,
                              void* d_out, int out_size, void* d_ws, size_t ws_size,
                              hipStream_t stream) {
  const float* x      = (const float*)d_in[0];
  const int*   ei     = (const int*)d_in[1];
  const float* Wf_l   = (const float*)d_in[2];
  const float* bf     = (const float*)d_in[3];
  const float* Wf_r   = (const float*)d_in[4];
  const float* W0_l   = (const float*)d_in[5];
  const float* b0     = (const float*)d_in[6];
  const float* W0_r   = (const float*)d_in[7];
  const float* W1_l   = (const float*)d_in[8];
  const float* b1     = (const float*)d_in[9];
  const float* W1_r   = (const float*)d_in[10];
  const float* W_lin  = (const float*)d_in[11];
  const float* b_lin  = (const float*)d_in[12];
  const float* W_lin2 = (const float*)d_in[13];
  const float* b_lin2 = (const float*)d_in[14];
  float* out = (float*)d_out;

  const int N = in_sizes[0] / 64;           // 50000
  const int E = in_sizes[1] / 2;            // 800000
  const int Npad = ((N + 127) / 128) * 128; // 50048
  const int nblkM = Npad / 128;
  const int NB = (N + 63) / 64;             // 782 buckets
  const int G  = 64;                        // partition blocks
  const int CH = (E + G - 1) / G;           // 12500 edges/block
  const int* e_src = ei;
  const int* e_tgt = ei + E;

  size_t off = 0;
  char* base = (char*)d_ws;
  auto carve = [&](size_t bytes) -> void* {
    void* p = base + off;
    off += (bytes + 255) & ~(size_t)255;
    return p;
  };
  int*      row_ptr = (int*)carve((size_t)(N + 1) * 4);
  int*      bcnt    = (int*)carve((size_t)NB * 4);
  int*      boff    = (int*)carve((size_t)(NB + 1) * 4);
  int*      histT   = (int*)carve((size_t)NB * G * 4);
  unsigned* vals    = (unsigned*)carve((size_t)E * 4);
  int*      srcs    = (int*)carve((size_t)(E + 16) * 4);
  unsigned short* xb    = (unsigned short*)carve((size_t)Npad * 64 * 2);
  unsigned short* mb    = (unsigned short*)carve((size_t)Npad * 64 * 2);
  unsigned short* h1b   = (unsigned short*)carve((size_t)Npad * 256 * 2);
  unsigned short* h2b   = (unsigned short*)carve((size_t)Npad * 128 * 2);
  unsigned short* yb    = (unsigned short*)carve((size_t)Npad * 128 * 2);
  unsigned short* zb    = (unsigned short*)carve((size_t)Npad * 128 * 2);
  unsigned short* Wt1hi = (unsigned short*)carve(256 * 128 * 2);
  unsigned short* Wt2hi = (unsigned short*)carve(256 * 256 * 2);
  unsigned short* Wt3hi = (unsigned short*)carve(256 * 128 * 2);
  float* Wcomb = (float*)carve(1024 * 4);
  float* bcomb = (float*)carve(8 * 4);
  (void)ws_size; (void)n_in; (void)out_size;

  const int nbConv = (N * 16 + 255) / 256;  // 3125
  const int nbPrep = nbConv + 128 + 256 + 128 + 4;
  const size_t ldsNB = (size_t)NB * 4;

  // CSR build: radix partition (no global atomics) + per-bucket sort (+prep merged)
  hist_k<<<G, 256, ldsNB, stream>>>(e_tgt, histT, E, NB, CH);
  scanb_k<<<(NB + 3) / 4, 256, 0, stream>>>(histT, bcnt, NB);
  bscan_k<<<1, 1024, 0, stream>>>(bcnt, boff, row_ptr, srcs, NB, E, N);
  scatter_k<<<G, 256, ldsNB, stream>>>(e_src, e_tgt, boff, histT, vals, E, NB, CH);
  bsort_prep_k<<<NB + nbPrep, 256, 0, stream>>>(
      vals, boff, row_ptr, srcs, N, NB,
      x, xb, nbConv, N * 16,
      Wf_l, Wf_r, Wt1hi,
      W0_l, W0_r, Wt2hi,
      W1_l, W1_r, Wt3hi,
      W_lin, b_lin, W_lin2, b_lin2, Wcomb, bcomb);

  const int nbAgg = (N + 3) / 4;
  const dim3 gemmGrid(nblkM, 2);

  // Layer 1: hi-only W (2 segs)
  agg_mean64_k<<<nbAgg, 256, 0, stream>>>(x, row_ptr, srcs, mb, N);
  {
    Segs s;
    s.n = 2;
    s.s[0] = {mb, Wt1hi,      64, 128, 64};
    s.s[1] = {xb, Wt1hi + 64, 64, 128, 64};
    s.s[2] = {nullptr, nullptr, 0, 0, 0};
    s.s[3] = {nullptr, nullptr, 0, 0, 0};
    gemm_mfma_k<1><<<gemmGrid, 256, 0, stream>>>(s, bf, nullptr, nullptr, h1b, 256);
  }

  // Layer 2: hi-only W
  {
    Segs s;
    s.n = 1;
    s.s[0] = {h1b, Wt2hi, 256, 256, 256};
    s.s[1] = {nullptr, nullptr, 0, 0, 0};
    s.s[2] = {nullptr, nullptr, 0, 0, 0};
    s.s[3] = {nullptr, nullptr, 0, 0, 0};
    gemm_mfma_k<0><<<gemmGrid, 256, 0, stream>>>(s, nullptr, yb, zb, nullptr, 256);
  }
  agg128_k<1><<<nbAgg, 256, 0, stream>>>(yb, zb, b0, row_ptr, srcs, h2b, nullptr, nullptr, N);

  // Layer 3 + fused head: hi-only W
  {
    Segs s;
    s.n = 1;
    s.s[0] = {h2b, Wt3hi, 128, 128, 128};
    s.s[1] = {nullptr, nullptr, 0, 0, 0};
    s.s[2] = {nullptr, nullptr, 0, 0, 0};
    s.s[3] = {nullptr, nullptr, 0, 0, 0};
    gemm_mfma_k<0><<<gemmGrid, 256, 0, stream>>>(s, nullptr, yb, zb, nullptr, 256);
  }
  agg128_k<2><<<nbAgg, 256, 0, stream>>>(yb, zb, b1, row_ptr, srcs, out, Wcomb, bcomb, N);
}

// Round 12
// 265.327 us; speedup vs baseline: 1.0760x; 1.0760x over previous
//
#include <hip/hip_runtime.h>
#include <hip/hip_fp16.h>

// GraphSAGE 3-layer + head, MI355X.
// R11 -> R12: fp8 Y payload REVERTED (failed: absmax 4.0e-5 > 2.6e-5; e4m3
//   worst-case tail ~6%/elem defeats RMS estimates - fp16 is the payload floor).
//   agg64 keeps bf16 xb gather (7x smaller noise, ~5e-6 contribution - safe).
//   This round's gain: CSR hist/scatter G=64 -> G=256 blocks (were using 25%
//   of CUs); new scanb scans 256 per-block counts per bucket (int4/lane +
//   wave scan + intra-lane prefix).
// Gather laws: one row per vmem instruction (R7); >=16 loads in flight (R8);
// no atomic funnels (R5); VALU trim below ~60% busy is neutral (R10);
// payload precision floor is fp16 (R11).

typedef __attribute__((ext_vector_type(8))) short bf16x8;
typedef __attribute__((ext_vector_type(4))) float f32x4;

struct Seg { const unsigned short* A; const unsigned short* W; int lda; int ldw; int K; };
struct Segs { Seg s[4]; int n; };

__device__ __forceinline__ unsigned short f2bf(float x) {
  unsigned u = __float_as_uint(x);
  u += 0x7FFF + ((u >> 16) & 1);   // RNE
  return (unsigned short)(u >> 16);
}
__device__ __forceinline__ unsigned short f2h(float x) {
  return __half_as_ushort(__float2half(x));
}
__device__ __forceinline__ float2 h2f2(unsigned u) {
  __half2 h = *reinterpret_cast<__half2*>(&u);
  return __half22float2(h);
}
__device__ __forceinline__ float2 ld_h2(const unsigned short* p, size_t idx) {
  return h2f2(*(const unsigned*)(p + idx));
}

// ---------------- CSR build: multi-block radix partition (G=256) ----------------
__global__ __launch_bounds__(256) void hist_k(const int* __restrict__ tgt, int* __restrict__ histT,
                                              int E, int NB, int CH) {
  extern __shared__ int sh[];
  int g = blockIdx.x, tid = threadIdx.x;
  for (int b = tid; b < NB; b += 256) sh[b] = 0;
  __syncthreads();
  int eb = g * CH, ee = min(eb + CH, E);
  for (int i = eb + tid; i < ee; i += 256)
    atomicAdd(&sh[tgt[i] >> 6], 1);
  __syncthreads();
  for (int b = tid; b < NB; b += 256) histT[b * 256 + g] = sh[b];
}

// one wave per bucket: scan 256 per-block counts (4 per lane) -> relative bases + bucket total
__global__ __launch_bounds__(256) void scanb_k(int* __restrict__ histT, int* __restrict__ bcnt, int NB) {
  int wv = threadIdx.x >> 6, lane = threadIdx.x & 63;
  int b = blockIdx.x * 4 + wv;
  if (b >= NB) return;
  int4 c = *(const int4*)&histT[b * 256 + lane * 4];
  int s = c.x + c.y + c.z + c.w;
  int x = s;
#pragma unroll
  for (int o = 1; o < 64; o <<= 1) {
    int y = __shfl_up(x, o);
    if (lane >= o) x += y;
  }
  int e = x - s;
  *(int4*)&histT[b * 256 + lane * 4] = make_int4(e, e + c.x, e + c.x + c.y, e + c.x + c.y + c.z);
  if (lane == 63) bcnt[b] = x;
}

__global__ __launch_bounds__(1024) void bscan_k(const int* __restrict__ bcnt, int* __restrict__ boff,
                                                int* __restrict__ row_ptr, int* __restrict__ srcs,
                                                int NB, int E, int N) {
  __shared__ int sh[1024];
  int tid = threadIdx.x;
  int v = (tid < NB) ? bcnt[tid] : 0;
  int val = v;
  sh[tid] = val;
  __syncthreads();
  for (int o = 1; o < 1024; o <<= 1) {
    int t = (tid >= o) ? sh[tid - o] : 0;
    __syncthreads();
    val += t;
    sh[tid] = val;
    __syncthreads();
  }
  if (tid < NB) boff[tid] = val - v;
  if (tid == NB - 1) boff[NB] = val;
  if (tid == 0) row_ptr[N] = E;
  if (tid < 16) srcs[E + tid] = 0;   // pad: aligned-block gather may read past E
}

__global__ __launch_bounds__(256) void scatter_k(const int* __restrict__ src, const int* __restrict__ tgt,
                                                 const int* __restrict__ boff, const int* __restrict__ histT,
                                                 unsigned* __restrict__ vals, int E, int NB, int CH) {
  extern __shared__ int sh[];
  int g = blockIdx.x, tid = threadIdx.x;
  for (int b = tid; b < NB; b += 256) sh[b] = boff[b] + histT[b * 256 + g];
  __syncthreads();
  int eb = g * CH, ee = min(eb + CH, E);
  for (int i = eb + tid; i < ee; i += 256) {
    int t = tgt[i], s = src[i];
    int pos = atomicAdd(&sh[t >> 6], 1);
    vals[pos] = (unsigned)s | ((unsigned)(t & 63) << 17);
  }
}

// ---------------- merged: per-bucket sort + prep (conv/packs/head fold) ----------------
__global__ __launch_bounds__(256) void bsort_prep_k(
    const unsigned* __restrict__ vals, const int* __restrict__ boff,
    int* __restrict__ row_ptr, int* __restrict__ srcs, int N, int NB,
    const float* __restrict__ x, unsigned short* __restrict__ xb, int nbConv, int n4,
    const float* __restrict__ Wf_l, const float* __restrict__ Wf_r, unsigned short* __restrict__ Wt1hi,
    const float* __restrict__ W0_l, const float* __restrict__ W0_r, unsigned short* __restrict__ Wt2hi,
    const float* __restrict__ W1_l, const float* __restrict__ W1_r, unsigned short* __restrict__ Wt3hi,
    const float* __restrict__ Wlin, const float* __restrict__ blin,
    const float* __restrict__ Wlin2, const float* __restrict__ blin2,
    float* __restrict__ Wc, float* __restrict__ bc) {
  int b = blockIdx.x, tid = threadIdx.x;
  if (b < NB) {                      // ---- bsort part ----
    int base = b << 6;
    int s0 = boff[b], s1 = boff[b + 1];
    __shared__ int hist[64], excl[64], cur[64];
    if (tid < 64) { hist[tid] = 0; cur[tid] = 0; }
    __syncthreads();
    for (int i = s0 + tid; i < s1; i += 256)
      atomicAdd(&hist[(vals[i] >> 17) & 63], 1);
    __syncthreads();
    if (tid < 64) {
      int v = hist[tid];
      int xx = v;
#pragma unroll
      for (int o = 1; o < 64; o <<= 1) {
        int y = __shfl_up(xx, o);
        if (tid >= o) xx += y;
      }
      excl[tid] = xx - v;
      int node = base + tid;
      if (node < N) row_ptr[node] = s0 + xx - v;
    }
    __syncthreads();
    for (int i = s0 + tid; i < s1; i += 256) {
      unsigned v = vals[i];
      int l = (v >> 17) & 63;
      int pos = s0 + excl[l] + atomicAdd(&cur[l], 1);
      srcs[pos] = (int)(v & 0x1FFFF);
    }
    return;
  }
  b -= NB;                           // ---- prep part ----
  if (b < nbConv) {
    int i = b * 256 + tid;
    if (i < n4) {
      float4 v = ((const float4*)x)[i];
      ((ushort2*)xb)[i * 2]     = make_ushort2(f2bf(v.x), f2bf(v.y));
      ((ushort2*)xb)[i * 2 + 1] = make_ushort2(f2bf(v.z), f2bf(v.w));
    }
    return;
  }
  b -= nbConv;
  if (b < 128) {             // L1 k-split pack, hi only: Wt1[n][k] (256 x 128)
    int idx = b * 256 + tid;
    int n = idx >> 7, k = idx & 127;
    float v = (k < 64) ? Wf_l[k * 256 + n] : Wf_r[(k - 64) * 256 + n];
    Wt1hi[idx] = f2bf(v);
    return;
  }
  b -= 128;
  if (b < 256) {             // L2 n-split pack: Wt2[n][k] (256 x 256)
    int idx = b * 256 + tid;
    int n = idx >> 8, k = idx & 255;
    float v = (n < 128) ? W0_l[k * 128 + n] : W0_r[k * 128 + (n - 128)];
    Wt2hi[idx] = f2bf(v);
    return;
  }
  b -= 256;
  if (b < 128) {             // L3 n-split pack: Wt3[n][k] (256 x 128)
    int idx = b * 256 + tid;
    int n = idx >> 7, k = idx & 127;
    float v = (n < 128) ? W1_l[k * 128 + n] : W1_r[k * 128 + (n - 128)];
    Wt3hi[idx] = f2bf(v);
    return;
  }
  b -= 128;
  {                          // head fold: 4 blocks
    int idx = b * 256 + tid;
    if (idx < 1024) {
      int i = idx >> 3, j = idx & 7;
      float acc = 0.f;
      for (int k = 0; k < 128; ++k) acc = fmaf(Wlin[i * 128 + k], Wlin2[k * 8 + j], acc);
      Wc[idx] = acc;
    }
    if (idx < 8) {
      float acc = blin2[idx];
      for (int k = 0; k < 128; ++k) acc = fmaf(blin[k], Wlin2[k * 8 + idx], acc);
      bc[idx] = acc;
    }
  }
}

// ---------------- aggregation ----------------
// wave per node, D=64, lane=dim, bf16 gather from xb (128B rows).
// Aligned-16 edge blocks; int4 srcs broadcast; wave-uniform masks.
__global__ __launch_bounds__(256) void agg_mean64_k(const unsigned short* __restrict__ xb, const int* __restrict__ rp,
                                                    const int* __restrict__ srcs, unsigned short* __restrict__ mb, int n) {
  int w = threadIdx.x >> 6, lane = threadIdx.x & 63;
  int node = blockIdx.x * 4 + w;
  if (node >= n) return;
  int s0 = __builtin_amdgcn_readfirstlane(rp[node]);
  int s1 = __builtin_amdgcn_readfirstlane(rp[node + 1]);
  const unsigned char* xB = (const unsigned char*)xb;
  unsigned db = (unsigned)lane * 2u;
  float sum = 0.f;
  for (int b = s0 & ~15; b < s1; b += 16) {
    int4 q0 = *(const int4*)&srcs[b];
    int4 q1 = *(const int4*)&srcs[b + 4];
    int4 q2 = *(const int4*)&srcs[b + 8];
    int4 q3 = *(const int4*)&srcs[b + 12];
    int idx[16] = {q0.x, q0.y, q0.z, q0.w, q1.x, q1.y, q1.z, q1.w,
                   q2.x, q2.y, q2.z, q2.w, q3.x, q3.y, q3.z, q3.w};
    unsigned short us[16];
#pragma unroll
    for (int i = 0; i < 16; ++i)
      us[i] = *(const unsigned short*)(xB + (((unsigned)idx[i] << 7) + db));
#pragma unroll
    for (int i = 0; i < 16; ++i) {
      float m = (b + i >= s0 && b + i < s1) ? 1.f : 0.f;   // uniform -> SALU
      float v = __uint_as_float((unsigned)us[i] << 16);
      sum = fmaf(m, v, sum);
    }
  }
  int deg = s1 - s0;
  float inv = 1.f / (float)(deg > 0 ? deg : 1);
  mb[(size_t)node * 64 + lane] = f2bf(sum * inv);
}

// wave per node, D=128, lane = 2 dims, fp16 gather (256B rows).
// OUTMODE 1: hout = bf16 h (N x 128). OUTMODE 2: fused head -> out fp32 (N x 8).
template <int OUTMODE>
__global__ __launch_bounds__(256) void agg128_k(const unsigned short* __restrict__ yb,
                                                const unsigned short* __restrict__ zb,
                                                const float* __restrict__ bias,
                                                const int* __restrict__ rp, const int* __restrict__ srcs,
                                                void* __restrict__ hout,
                                                const float* __restrict__ Wc, const float* __restrict__ bc, int n) {
  int w = threadIdx.x >> 6, lane = threadIdx.x & 63;
  int node = blockIdx.x * 4 + w;
  if (node >= n) return;
  int s0 = __builtin_amdgcn_readfirstlane(rp[node]);
  int s1 = __builtin_amdgcn_readfirstlane(rp[node + 1]);
  const unsigned char* ybB = (const unsigned char*)yb;
  unsigned db = (unsigned)lane * 4u;
  int d = lane * 2;
  float sx = 0.f, sy = 0.f;
  for (int b = s0 & ~15; b < s1; b += 16) {
    int4 q0 = *(const int4*)&srcs[b];
    int4 q1 = *(const int4*)&srcs[b + 4];
    int4 q2 = *(const int4*)&srcs[b + 8];
    int4 q3 = *(const int4*)&srcs[b + 12];
    int idx[16] = {q0.x, q0.y, q0.z, q0.w, q1.x, q1.y, q1.z, q1.w,
                   q2.x, q2.y, q2.z, q2.w, q3.x, q3.y, q3.z, q3.w};
    unsigned uv[16];
#pragma unroll
    for (int i = 0; i < 16; ++i)
      uv[i] = *(const unsigned*)(ybB + (((unsigned)idx[i] << 8) + db));
#pragma unroll
    for (int i = 0; i < 16; ++i) {
      float m = (b + i >= s0 && b + i < s1) ? 1.f : 0.f;   // uniform -> SALU
      float2 v = h2f2(uv[i]);
      sx = fmaf(m, v.x, sx);
      sy = fmaf(m, v.y, sy);
    }
  }
  int deg = s1 - s0;
  float inv = 1.f / (float)(deg > 0 ? deg : 1);
  float2 z = ld_h2(zb, (size_t)node * 128 + d);
  float2 b2 = *(const float2*)&bias[d];
  float ox = fmaxf(fmaf(sx, inv, z.x + b2.x), 0.f);
  float oy = fmaxf(fmaf(sy, inv, z.y + b2.y), 0.f);

  if (OUTMODE == 1) {
    ((ushort2*)hout)[((size_t)node * 128 + d) / 2] = make_ushort2(f2bf(ox), f2bf(oy));
  } else {
    // fused head: out[node][j] = sum_d o_d * Wc[d][j] + bc[j]
    const float4* wr = (const float4*)&Wc[d * 8];
    float4 wa0 = wr[0], wa1 = wr[1], wb0 = wr[2], wb1 = wr[3];
    float a8[8];
    a8[0] = ox * wa0.x + oy * wb0.x;
    a8[1] = ox * wa0.y + oy * wb0.y;
    a8[2] = ox * wa0.z + oy * wb0.z;
    a8[3] = ox * wa0.w + oy * wb0.w;
    a8[4] = ox * wa1.x + oy * wb1.x;
    a8[5] = ox * wa1.y + oy * wb1.y;
    a8[6] = ox * wa1.z + oy * wb1.z;
    a8[7] = ox * wa1.w + oy * wb1.w;
#pragma unroll
    for (int off = 32; off >= 1; off >>= 1) {
#pragma unroll
      for (int j = 0; j < 8; ++j) a8[j] += __shfl_xor(a8[j], off);
    }
    if (lane == 0) {
      float* o = (float*)hout + (size_t)node * 8;
      *(float4*)o       = make_float4(a8[0] + bc[0], a8[1] + bc[1], a8[2] + bc[2], a8[3] + bc[3]);
      *(float4*)(o + 4) = make_float4(a8[4] + bc[4], a8[5] + bc[5], a8[6] + bc[6], a8[7] + bc[7]);
    }
  }
}

// ---------------- MFMA GEMM ----------------
// Block tile 128x128, 4 waves (2x2), each wave 64x64 via 4x4 frags of 16x16x32 bf16 MFMA.
// MODE 0: fp16 out, split into Y (cols 0..127) / Z (cols 128..255), ld 128.
// MODE 1: bias+relu -> bf16 out Ob (ldc 256).
template <int MODE>
__global__ __launch_bounds__(256) void gemm_mfma_k(Segs segs, const float* __restrict__ bias,
                                                   unsigned short* __restrict__ Y, unsigned short* __restrict__ Z,
                                                   unsigned short* __restrict__ Ob, int ldc) {
  __shared__ unsigned short Asl[128 * 32];
  __shared__ unsigned short Wsl[128 * 32];
  int tid = threadIdx.x;
  int lane = tid & 63, wave = tid >> 6;
  int wm = wave & 1, wn = wave >> 1;
  int rowBase = blockIdx.x * 128, colBase = blockIdx.y * 128;
  f32x4 acc[4][4] = {};

  int c0 = tid, c1 = tid + 256;
  int r0 = c0 >> 2, q0 = c0 & 3;
  int r1 = c1 >> 2, q1 = c1 & 3;
  int ml = lane & 15, qq = lane >> 4;

  for (int si = 0; si < segs.n; ++si) {
    const unsigned short* Aseg = segs.s[si].A;
    const unsigned short* Wseg = segs.s[si].W;
    int lda = segs.s[si].lda, ldw = segs.s[si].ldw, K = segs.s[si].K;
    for (int k0 = 0; k0 < K; k0 += 32) {
      uint4 av0 = *(const uint4*)&Aseg[(size_t)(rowBase + r0) * lda + k0 + q0 * 8];
      uint4 av1 = *(const uint4*)&Aseg[(size_t)(rowBase + r1) * lda + k0 + q1 * 8];
      uint4 wv0 = *(const uint4*)&Wseg[(size_t)(colBase + r0) * ldw + k0 + q0 * 8];
      uint4 wv1 = *(const uint4*)&Wseg[(size_t)(colBase + r1) * ldw + k0 + q1 * 8];
      __syncthreads();
      *(uint4*)&Asl[c0 * 8] = av0;
      *(uint4*)&Asl[c1 * 8] = av1;
      *(uint4*)&Wsl[c0 * 8] = wv0;
      *(uint4*)&Wsl[c1 * 8] = wv1;
      __syncthreads();
      bf16x8 af[4], bw[4];
#pragma unroll
      for (int i = 0; i < 4; ++i) {
        af[i] = *(bf16x8*)&Asl[(wm * 64 + i * 16 + ml) * 32 + qq * 8];
        bw[i] = *(bf16x8*)&Wsl[(wn * 64 + i * 16 + ml) * 32 + qq * 8];
      }
#pragma unroll
      for (int mf = 0; mf < 4; ++mf)
#pragma unroll
        for (int nf = 0; nf < 4; ++nf)
          acc[mf][nf] = __builtin_amdgcn_mfma_f32_16x16x32_bf16(af[mf], bw[nf], acc[mf][nf], 0, 0, 0);
    }
  }

  if (MODE == 0) {
    unsigned short* dst = (colBase == 0) ? Y : Z;
#pragma unroll
    for (int mf = 0; mf < 4; ++mf) {
      int row = rowBase + wm * 64 + mf * 16 + qq * 4;
#pragma unroll
      for (int nf = 0; nf < 4; ++nf) {
        int col = wn * 64 + nf * 16 + ml;
#pragma unroll
        for (int r = 0; r < 4; ++r)
          dst[(size_t)(row + r) * 128 + col] = f2h(acc[mf][nf][r]);
      }
    }
  } else {
    float bc4[4];
#pragma unroll
    for (int nf = 0; nf < 4; ++nf) bc4[nf] = bias[colBase + wn * 64 + nf * 16 + ml];
#pragma unroll
    for (int mf = 0; mf < 4; ++mf) {
      int row = rowBase + wm * 64 + mf * 16 + qq * 4;
#pragma unroll
      for (int nf = 0; nf < 4; ++nf) {
        int col = colBase + wn * 64 + nf * 16 + ml;
#pragma unroll
        for (int r = 0; r < 4; ++r) {
          float o = fmaxf(acc[mf][nf][r] + bc4[nf], 0.f);
          Ob[(size_t)(row + r) * ldc + col] = f2bf(o);
        }
      }
    }
  }
}

// ---------------- host ----------------
extern "C" void kernel_launch(void* const* d_in, const int* in_sizes, int n_in,
                              void* d_out, int out_size, void* d_ws, size_t ws_size,
                              hipStream_t stream) {
  const float* x      = (const float*)d_in[0];
  const int*   ei     = (const int*)d_in[1];
  const float* Wf_l   = (const float*)d_in[2];
  const float* bf     = (const float*)d_in[3];
  const float* Wf_r   = (const float*)d_in[4];
  const float* W0_l   = (const float*)d_in[5];
  const float* b0     = (const float*)d_in[6];
  const float* W0_r   = (const float*)d_in[7];
  const float* W1_l   = (const float*)d_in[8];
  const float* b1     = (const float*)d_in[9];
  const float* W1_r   = (const float*)d_in[10];
  const float* W_lin  = (const float*)d_in[11];
  const float* b_lin  = (const float*)d_in[12];
  const float* W_lin2 = (const float*)d_in[13];
  const float* b_lin2 = (const float*)d_in[14];
  float* out = (float*)d_out;

  const int N = in_sizes[0] / 64;           // 50000
  const int E = in_sizes[1] / 2;            // 800000
  const int Npad = ((N + 127) / 128) * 128; // 50048
  const int nblkM = Npad / 128;
  const int NB = (N + 63) / 64;             // 782 buckets
  const int G  = 256;                       // partition blocks (1 per CU)
  const int CH = (E + G - 1) / G;           // 3125 edges/block
  const int* e_src = ei;
  const int* e_tgt = ei + E;

  size_t off = 0;
  char* base = (char*)d_ws;
  auto carve = [&](size_t bytes) -> void* {
    void* p = base + off;
    off += (bytes + 255) & ~(size_t)255;
    return p;
  };
  int*      row_ptr = (int*)carve((size_t)(N + 1) * 4);
  int*      bcnt    = (int*)carve((size_t)NB * 4);
  int*      boff    = (int*)carve((size_t)(NB + 1) * 4);
  int*      histT   = (int*)carve((size_t)NB * G * 4);
  unsigned* vals    = (unsigned*)carve((size_t)E * 4);
  int*      srcs    = (int*)carve((size_t)(E + 16) * 4);
  unsigned short* xb    = (unsigned short*)carve((size_t)Npad * 64 * 2);
  unsigned short* mb    = (unsigned short*)carve((size_t)Npad * 64 * 2);
  unsigned short* h1b   = (unsigned short*)carve((size_t)Npad * 256 * 2);
  unsigned short* h2b   = (unsigned short*)carve((size_t)Npad * 128 * 2);
  unsigned short* yb    = (unsigned short*)carve((size_t)Npad * 128 * 2);
  unsigned short* zb    = (unsigned short*)carve((size_t)Npad * 128 * 2);
  unsigned short* Wt1hi = (unsigned short*)carve(256 * 128 * 2);
  unsigned short* Wt2hi = (unsigned short*)carve(256 * 256 * 2);
  unsigned short* Wt3hi = (unsigned short*)carve(256 * 128 * 2);
  float* Wcomb = (float*)carve(1024 * 4);
  float* bcomb = (float*)carve(8 * 4);
  (void)ws_size; (void)n_in; (void)out_size;

  const int nbConv = (N * 16 + 255) / 256;  // 3125
  const int nbPrep = nbConv + 128 + 256 + 128 + 4;
  const size_t ldsNB = (size_t)NB * 4;

  // CSR build: radix partition (no global atomics) + per-bucket sort (+prep merged)
  hist_k<<<G, 256, ldsNB, stream>>>(e_tgt, histT, E, NB, CH);
  scanb_k<<<(NB + 3) / 4, 256, 0, stream>>>(histT, bcnt, NB);
  bscan_k<<<1, 1024, 0, stream>>>(bcnt, boff, row_ptr, srcs, NB, E, N);
  scatter_k<<<G, 256, ldsNB, stream>>>(e_src, e_tgt, boff, histT, vals, E, NB, CH);
  bsort_prep_k<<<NB + nbPrep, 256, 0, stream>>>(
      vals, boff, row_ptr, srcs, N, NB,
      x, xb, nbConv, N * 16,
      Wf_l, Wf_r, Wt1hi,
      W0_l, W0_r, Wt2hi,
      W1_l, W1_r, Wt3hi,
      W_lin, b_lin, W_lin2, b_lin2, Wcomb, bcomb);

  const int nbAgg = (N + 3) / 4;
  const dim3 gemmGrid(nblkM, 2);

  // Layer 1: hi-only W (2 segs); agg64 gathers bf16 xb
  agg_mean64_k<<<nbAgg, 256, 0, stream>>>(xb, row_ptr, srcs, mb, N);
  {
    Segs s;
    s.n = 2;
    s.s[0] = {mb, Wt1hi,      64, 128, 64};
    s.s[1] = {xb, Wt1hi + 64, 64, 128, 64};
    s.s[2] = {nullptr, nullptr, 0, 0, 0};
    s.s[3] = {nullptr, nullptr, 0, 0, 0};
    gemm_mfma_k<1><<<gemmGrid, 256, 0, stream>>>(s, bf, nullptr, nullptr, h1b, 256);
  }

  // Layer 2: Y|Z fp16
  {
    Segs s;
    s.n = 1;
    s.s[0] = {h1b, Wt2hi, 256, 256, 256};
    s.s[1] = {nullptr, nullptr, 0, 0, 0};
    s.s[2] = {nullptr, nullptr, 0, 0, 0};
    s.s[3] = {nullptr, nullptr, 0, 0, 0};
    gemm_mfma_k<0><<<gemmGrid, 256, 0, stream>>>(s, nullptr, yb, zb, nullptr, 256);
  }
  agg128_k<1><<<nbAgg, 256, 0, stream>>>(yb, zb, b0, row_ptr, srcs, h2b, nullptr, nullptr, N);

  // Layer 3 + fused head
  {
    Segs s;
    s.n = 1;
    s.s[0] = {h2b, Wt3hi, 128, 128, 128};
    s.s[1] = {nullptr, nullptr, 0, 0, 0};
    s.s[2] = {nullptr, nullptr, 0, 0, 0};
    s.s[3] = {nullptr, nullptr, 0, 0, 0};
    gemm_mfma_k<0><<<gemmGrid, 256, 0, stream>>>(s, nullptr, yb, zb, nullptr, 256);
  }
  agg128_k<2><<<nbAgg, 256, 0, stream>>>(yb, zb, b1, row_ptr, srcs, out, Wcomb, bcomb, N);
}

// Round 13
// 264.671 us; speedup vs baseline: 1.0787x; 1.0025x over previous
//
#include <hip/hip_runtime.h>
#include <hip/hip_fp16.h>

// GraphSAGE 3-layer + head, MI355X.
// R12 -> R13: GEMM staging switched to async global_load_lds width=16 (the
//   m93->m97 ladder lever: kills the global->VGPR->LDS round trip; compiler
//   never auto-emits it). LDS chunk layout (chunk = tid, 16B each) is already
//   the required wave-uniform-base + lane*16 contiguous order - drop-in.
//   Everything else frozen at R12 (265 us).
// Laws: one row per gather instruction (R7); >=16 loads in flight (R8); no
// atomic funnels (R5); VALU trim below ~60% busy neutral (R10); gather payload
// precision floor is fp16 (R11); aggs are at the random-gather fabric floor.

typedef __attribute__((ext_vector_type(8))) short bf16x8;
typedef __attribute__((ext_vector_type(4))) float f32x4;

struct Seg { const unsigned short* A; const unsigned short* W; int lda; int ldw; int K; };
struct Segs { Seg s[4]; int n; };

__device__ __forceinline__ unsigned short f2bf(float x) {
  unsigned u = __float_as_uint(x);
  u += 0x7FFF + ((u >> 16) & 1);   // RNE
  return (unsigned short)(u >> 16);
}
__device__ __forceinline__ unsigned short f2h(float x) {
  return __half_as_ushort(__float2half(x));
}
__device__ __forceinline__ float2 h2f2(unsigned u) {
  __half2 h = *reinterpret_cast<__half2*>(&u);
  return __half22float2(h);
}
__device__ __forceinline__ float2 ld_h2(const unsigned short* p, size_t idx) {
  return h2f2(*(const unsigned*)(p + idx));
}
__device__ __forceinline__ void gload_lds16(const void* g, void* l) {
  __builtin_amdgcn_global_load_lds(
      (const __attribute__((address_space(1))) unsigned int*)g,
      (__attribute__((address_space(3))) unsigned int*)l, 16, 0, 0);
}

// ---------------- CSR build: multi-block radix partition (G=256) ----------------
__global__ __launch_bounds__(256) void hist_k(const int* __restrict__ tgt, int* __restrict__ histT,
                                              int E, int NB, int CH) {
  extern __shared__ int sh[];
  int g = blockIdx.x, tid = threadIdx.x;
  for (int b = tid; b < NB; b += 256) sh[b] = 0;
  __syncthreads();
  int eb = g * CH, ee = min(eb + CH, E);
  for (int i = eb + tid; i < ee; i += 256)
    atomicAdd(&sh[tgt[i] >> 6], 1);
  __syncthreads();
  for (int b = tid; b < NB; b += 256) histT[b * 256 + g] = sh[b];
}

// one wave per bucket: scan 256 per-block counts (4 per lane) -> relative bases + bucket total
__global__ __launch_bounds__(256) void scanb_k(int* __restrict__ histT, int* __restrict__ bcnt, int NB) {
  int wv = threadIdx.x >> 6, lane = threadIdx.x & 63;
  int b = blockIdx.x * 4 + wv;
  if (b >= NB) return;
  int4 c = *(const int4*)&histT[b * 256 + lane * 4];
  int s = c.x + c.y + c.z + c.w;
  int x = s;
#pragma unroll
  for (int o = 1; o < 64; o <<= 1) {
    int y = __shfl_up(x, o);
    if (lane >= o) x += y;
  }
  int e = x - s;
  *(int4*)&histT[b * 256 + lane * 4] = make_int4(e, e + c.x, e + c.x + c.y, e + c.x + c.y + c.z);
  if (lane == 63) bcnt[b] = x;
}

__global__ __launch_bounds__(1024) void bscan_k(const int* __restrict__ bcnt, int* __restrict__ boff,
                                                int* __restrict__ row_ptr, int* __restrict__ srcs,
                                                int NB, int E, int N) {
  __shared__ int sh[1024];
  int tid = threadIdx.x;
  int v = (tid < NB) ? bcnt[tid] : 0;
  int val = v;
  sh[tid] = val;
  __syncthreads();
  for (int o = 1; o < 1024; o <<= 1) {
    int t = (tid >= o) ? sh[tid - o] : 0;
    __syncthreads();
    val += t;
    sh[tid] = val;
    __syncthreads();
  }
  if (tid < NB) boff[tid] = val - v;
  if (tid == NB - 1) boff[NB] = val;
  if (tid == 0) row_ptr[N] = E;
  if (tid < 16) srcs[E + tid] = 0;   // pad: aligned-block gather may read past E
}

__global__ __launch_bounds__(256) void scatter_k(const int* __restrict__ src, const int* __restrict__ tgt,
                                                 const int* __restrict__ boff, const int* __restrict__ histT,
                                                 unsigned* __restrict__ vals, int E, int NB, int CH) {
  extern __shared__ int sh[];
  int g = blockIdx.x, tid = threadIdx.x;
  for (int b = tid; b < NB; b += 256) sh[b] = boff[b] + histT[b * 256 + g];
  __syncthreads();
  int eb = g * CH, ee = min(eb + CH, E);
  for (int i = eb + tid; i < ee; i += 256) {
    int t = tgt[i], s = src[i];
    int pos = atomicAdd(&sh[t >> 6], 1);
    vals[pos] = (unsigned)s | ((unsigned)(t & 63) << 17);
  }
}

// ---------------- merged: per-bucket sort + prep (conv/packs/head fold) ----------------
__global__ __launch_bounds__(256) void bsort_prep_k(
    const unsigned* __restrict__ vals, const int* __restrict__ boff,
    int* __restrict__ row_ptr, int* __restrict__ srcs, int N, int NB,
    const float* __restrict__ x, unsigned short* __restrict__ xb, int nbConv, int n4,
    const float* __restrict__ Wf_l, const float* __restrict__ Wf_r, unsigned short* __restrict__ Wt1hi,
    const float* __restrict__ W0_l, const float* __restrict__ W0_r, unsigned short* __restrict__ Wt2hi,
    const float* __restrict__ W1_l, const float* __restrict__ W1_r, unsigned short* __restrict__ Wt3hi,
    const float* __restrict__ Wlin, const float* __restrict__ blin,
    const float* __restrict__ Wlin2, const float* __restrict__ blin2,
    float* __restrict__ Wc, float* __restrict__ bc) {
  int b = blockIdx.x, tid = threadIdx.x;
  if (b < NB) {                      // ---- bsort part ----
    int base = b << 6;
    int s0 = boff[b], s1 = boff[b + 1];
    __shared__ int hist[64], excl[64], cur[64];
    if (tid < 64) { hist[tid] = 0; cur[tid] = 0; }
    __syncthreads();
    for (int i = s0 + tid; i < s1; i += 256)
      atomicAdd(&hist[(vals[i] >> 17) & 63], 1);
    __syncthreads();
    if (tid < 64) {
      int v = hist[tid];
      int xx = v;
#pragma unroll
      for (int o = 1; o < 64; o <<= 1) {
        int y = __shfl_up(xx, o);
        if (tid >= o) xx += y;
      }
      excl[tid] = xx - v;
      int node = base + tid;
      if (node < N) row_ptr[node] = s0 + xx - v;
    }
    __syncthreads();
    for (int i = s0 + tid; i < s1; i += 256) {
      unsigned v = vals[i];
      int l = (v >> 17) & 63;
      int pos = s0 + excl[l] + atomicAdd(&cur[l], 1);
      srcs[pos] = (int)(v & 0x1FFFF);
    }
    return;
  }
  b -= NB;                           // ---- prep part ----
  if (b < nbConv) {
    int i = b * 256 + tid;
    if (i < n4) {
      float4 v = ((const float4*)x)[i];
      ((ushort2*)xb)[i * 2]     = make_ushort2(f2bf(v.x), f2bf(v.y));
      ((ushort2*)xb)[i * 2 + 1] = make_ushort2(f2bf(v.z), f2bf(v.w));
    }
    return;
  }
  b -= nbConv;
  if (b < 128) {             // L1 k-split pack, hi only: Wt1[n][k] (256 x 128)
    int idx = b * 256 + tid;
    int n = idx >> 7, k = idx & 127;
    float v = (k < 64) ? Wf_l[k * 256 + n] : Wf_r[(k - 64) * 256 + n];
    Wt1hi[idx] = f2bf(v);
    return;
  }
  b -= 128;
  if (b < 256) {             // L2 n-split pack: Wt2[n][k] (256 x 256)
    int idx = b * 256 + tid;
    int n = idx >> 8, k = idx & 255;
    float v = (n < 128) ? W0_l[k * 128 + n] : W0_r[k * 128 + (n - 128)];
    Wt2hi[idx] = f2bf(v);
    return;
  }
  b -= 256;
  if (b < 128) {             // L3 n-split pack: Wt3[n][k] (256 x 128)
    int idx = b * 256 + tid;
    int n = idx >> 7, k = idx & 127;
    float v = (n < 128) ? W1_l[k * 128 + n] : W1_r[k * 128 + (n - 128)];
    Wt3hi[idx] = f2bf(v);
    return;
  }
  b -= 128;
  {                          // head fold: 4 blocks
    int idx = b * 256 + tid;
    if (idx < 1024) {
      int i = idx >> 3, j = idx & 7;
      float acc = 0.f;
      for (int k = 0; k < 128; ++k) acc = fmaf(Wlin[i * 128 + k], Wlin2[k * 8 + j], acc);
      Wc[idx] = acc;
    }
    if (idx < 8) {
      float acc = blin2[idx];
      for (int k = 0; k < 128; ++k) acc = fmaf(blin[k], Wlin2[k * 8 + idx], acc);
      bc[idx] = acc;
    }
  }
}

// ---------------- aggregation ----------------
// wave per node, D=64, lane=dim, bf16 gather from xb (128B rows).
// Aligned-16 edge blocks; int4 srcs broadcast; wave-uniform masks.
__global__ __launch_bounds__(256) void agg_mean64_k(const unsigned short* __restrict__ xb, const int* __restrict__ rp,
                                                    const int* __restrict__ srcs, unsigned short* __restrict__ mb, int n) {
  int w = threadIdx.x >> 6, lane = threadIdx.x & 63;
  int node = blockIdx.x * 4 + w;
  if (node >= n) return;
  int s0 = __builtin_amdgcn_readfirstlane(rp[node]);
  int s1 = __builtin_amdgcn_readfirstlane(rp[node + 1]);
  const unsigned char* xB = (const unsigned char*)xb;
  unsigned db = (unsigned)lane * 2u;
  float sum = 0.f;
  for (int b = s0 & ~15; b < s1; b += 16) {
    int4 q0 = *(const int4*)&srcs[b];
    int4 q1 = *(const int4*)&srcs[b + 4];
    int4 q2 = *(const int4*)&srcs[b + 8];
    int4 q3 = *(const int4*)&srcs[b + 12];
    int idx[16] = {q0.x, q0.y, q0.z, q0.w, q1.x, q1.y, q1.z, q1.w,
                   q2.x, q2.y, q2.z, q2.w, q3.x, q3.y, q3.z, q3.w};
    unsigned short us[16];
#pragma unroll
    for (int i = 0; i < 16; ++i)
      us[i] = *(const unsigned short*)(xB + (((unsigned)idx[i] << 7) + db));
#pragma unroll
    for (int i = 0; i < 16; ++i) {
      float m = (b + i >= s0 && b + i < s1) ? 1.f : 0.f;   // uniform -> SALU
      float v = __uint_as_float((unsigned)us[i] << 16);
      sum = fmaf(m, v, sum);
    }
  }
  int deg = s1 - s0;
  float inv = 1.f / (float)(deg > 0 ? deg : 1);
  mb[(size_t)node * 64 + lane] = f2bf(sum * inv);
}

// wave per node, D=128, lane = 2 dims, fp16 gather (256B rows).
// OUTMODE 1: hout = bf16 h (N x 128). OUTMODE 2: fused head -> out fp32 (N x 8).
template <int OUTMODE>
__global__ __launch_bounds__(256) void agg128_k(const unsigned short* __restrict__ yb,
                                                const unsigned short* __restrict__ zb,
                                                const float* __restrict__ bias,
                                                const int* __restrict__ rp, const int* __restrict__ srcs,
                                                void* __restrict__ hout,
                                                const float* __restrict__ Wc, const float* __restrict__ bc, int n) {
  int w = threadIdx.x >> 6, lane = threadIdx.x & 63;
  int node = blockIdx.x * 4 + w;
  if (node >= n) return;
  int s0 = __builtin_amdgcn_readfirstlane(rp[node]);
  int s1 = __builtin_amdgcn_readfirstlane(rp[node + 1]);
  const unsigned char* ybB = (const unsigned char*)yb;
  unsigned db = (unsigned)lane * 4u;
  int d = lane * 2;
  float sx = 0.f, sy = 0.f;
  for (int b = s0 & ~15; b < s1; b += 16) {
    int4 q0 = *(const int4*)&srcs[b];
    int4 q1 = *(const int4*)&srcs[b + 4];
    int4 q2 = *(const int4*)&srcs[b + 8];
    int4 q3 = *(const int4*)&srcs[b + 12];
    int idx[16] = {q0.x, q0.y, q0.z, q0.w, q1.x, q1.y, q1.z, q1.w,
                   q2.x, q2.y, q2.z, q2.w, q3.x, q3.y, q3.z, q3.w};
    unsigned uv[16];
#pragma unroll
    for (int i = 0; i < 16; ++i)
      uv[i] = *(const unsigned*)(ybB + (((unsigned)idx[i] << 8) + db));
#pragma unroll
    for (int i = 0; i < 16; ++i) {
      float m = (b + i >= s0 && b + i < s1) ? 1.f : 0.f;   // uniform -> SALU
      float2 v = h2f2(uv[i]);
      sx = fmaf(m, v.x, sx);
      sy = fmaf(m, v.y, sy);
    }
  }
  int deg = s1 - s0;
  float inv = 1.f / (float)(deg > 0 ? deg : 1);
  float2 z = ld_h2(zb, (size_t)node * 128 + d);
  float2 b2 = *(const float2*)&bias[d];
  float ox = fmaxf(fmaf(sx, inv, z.x + b2.x), 0.f);
  float oy = fmaxf(fmaf(sy, inv, z.y + b2.y), 0.f);

  if (OUTMODE == 1) {
    ((ushort2*)hout)[((size_t)node * 128 + d) / 2] = make_ushort2(f2bf(ox), f2bf(oy));
  } else {
    // fused head: out[node][j] = sum_d o_d * Wc[d][j] + bc[j]
    const float4* wr = (const float4*)&Wc[d * 8];
    float4 wa0 = wr[0], wa1 = wr[1], wb0 = wr[2], wb1 = wr[3];
    float a8[8];
    a8[0] = ox * wa0.x + oy * wb0.x;
    a8[1] = ox * wa0.y + oy * wb0.y;
    a8[2] = ox * wa0.z + oy * wb0.z;
    a8[3] = ox * wa0.w + oy * wb0.w;
    a8[4] = ox * wa1.x + oy * wb1.x;
    a8[5] = ox * wa1.y + oy * wb1.y;
    a8[6] = ox * wa1.z + oy * wb1.z;
    a8[7] = ox * wa1.w + oy * wb1.w;
#pragma unroll
    for (int off = 32; off >= 1; off >>= 1) {
#pragma unroll
      for (int j = 0; j < 8; ++j) a8[j] += __shfl_xor(a8[j], off);
    }
    if (lane == 0) {
      float* o = (float*)hout + (size_t)node * 8;
      *(float4*)o       = make_float4(a8[0] + bc[0], a8[1] + bc[1], a8[2] + bc[2], a8[3] + bc[3]);
      *(float4*)(o + 4) = make_float4(a8[4] + bc[4], a8[5] + bc[5], a8[6] + bc[6], a8[7] + bc[7]);
    }
  }
}

// ---------------- MFMA GEMM ----------------
// Block tile 128x128, 4 waves (2x2), each wave 64x64 via 4x4 frags of 16x16x32 bf16 MFMA.
// Staging via async global_load_lds width=16 (wave-uniform base + lane*16; chunk=tid order).
// MODE 0: fp16 out, split into Y (cols 0..127) / Z (cols 128..255), ld 128.
// MODE 1: bias+relu -> bf16 out Ob (ldc 256).
template <int MODE>
__global__ __launch_bounds__(256) void gemm_mfma_k(Segs segs, const float* __restrict__ bias,
                                                   unsigned short* __restrict__ Y, unsigned short* __restrict__ Z,
                                                   unsigned short* __restrict__ Ob, int ldc) {
  __shared__ unsigned short Asl[128 * 32];
  __shared__ unsigned short Wsl[128 * 32];
  int tid = threadIdx.x;
  int lane = tid & 63, wave = tid >> 6;
  int wm = wave & 1, wn = wave >> 1;
  int rowBase = blockIdx.x * 128, colBase = blockIdx.y * 128;
  f32x4 acc[4][4] = {};

  int c0 = tid, c1 = tid + 256;
  int r0 = c0 >> 2, q0 = c0 & 3;
  int r1 = c1 >> 2, q1 = c1 & 3;
  int ml = lane & 15, qq = lane >> 4;

  for (int si = 0; si < segs.n; ++si) {
    const unsigned short* Aseg = segs.s[si].A;
    const unsigned short* Wseg = segs.s[si].W;
    int lda = segs.s[si].lda, ldw = segs.s[si].ldw, K = segs.s[si].K;
    for (int k0 = 0; k0 < K; k0 += 32) {
      __syncthreads();               // all waves done reading previous tile
      gload_lds16(&Aseg[(size_t)(rowBase + r0) * lda + k0 + q0 * 8], &Asl[c0 * 8]);
      gload_lds16(&Aseg[(size_t)(rowBase + r1) * lda + k0 + q1 * 8], &Asl[c1 * 8]);
      gload_lds16(&Wseg[(size_t)(colBase + r0) * ldw + k0 + q0 * 8], &Wsl[c0 * 8]);
      gload_lds16(&Wseg[(size_t)(colBase + r1) * ldw + k0 + q1 * 8], &Wsl[c1 * 8]);
      __syncthreads();               // drain async LDS writes (vmcnt) + barrier
      bf16x8 af[4], bw[4];
#pragma unroll
      for (int i = 0; i < 4; ++i) {
        af[i] = *(bf16x8*)&Asl[(wm * 64 + i * 16 + ml) * 32 + qq * 8];
        bw[i] = *(bf16x8*)&Wsl[(wn * 64 + i * 16 + ml) * 32 + qq * 8];
      }
#pragma unroll
      for (int mf = 0; mf < 4; ++mf)
#pragma unroll
        for (int nf = 0; nf < 4; ++nf)
          acc[mf][nf] = __builtin_amdgcn_mfma_f32_16x16x32_bf16(af[mf], bw[nf], acc[mf][nf], 0, 0, 0);
    }
  }

  if (MODE == 0) {
    unsigned short* dst = (colBase == 0) ? Y : Z;
#pragma unroll
    for (int mf = 0; mf < 4; ++mf) {
      int row = rowBase + wm * 64 + mf * 16 + qq * 4;
#pragma unroll
      for (int nf = 0; nf < 4; ++nf) {
        int col = wn * 64 + nf * 16 + ml;
#pragma unroll
        for (int r = 0; r < 4; ++r)
          dst[(size_t)(row + r) * 128 + col] = f2h(acc[mf][nf][r]);
      }
    }
  } else {
    float bc4[4];
#pragma unroll
    for (int nf = 0; nf < 4; ++nf) bc4[nf] = bias[colBase + wn * 64 + nf * 16 + ml];
#pragma unroll
    for (int mf = 0; mf < 4; ++mf) {
      int row = rowBase + wm * 64 + mf * 16 + qq * 4;
#pragma unroll
      for (int nf = 0; nf < 4; ++nf) {
        int col = colBase + wn * 64 + nf * 16 + ml;
#pragma unroll
        for (int r = 0; r < 4; ++r) {
          float o = fmaxf(acc[mf][nf][r] + bc4[nf], 0.f);
          Ob[(size_t)(row + r) * ldc + col] = f2bf(o);
        }
      }
    }
  }
}

// ---------------- host ----------------
extern "C" void kernel_launch(void* const* d_in, const int* in_sizes, int n_in,
                              void* d_out, int out_size, void* d_ws, size_t ws_size,
                              hipStream_t stream) {
  const float* x      = (const float*)d_in[0];
  const int*   ei     = (const int*)d_in[1];
  const float* Wf_l   = (const float*)d_in[2];
  const float* bf     = (const float*)d_in[3];
  const float* Wf_r   = (const float*)d_in[4];
  const float* W0_l   = (const float*)d_in[5];
  const float* b0     = (const float*)d_in[6];
  const float* W0_r   = (const float*)d_in[7];
  const float* W1_l   = (const float*)d_in[8];
  const float* b1     = (const float*)d_in[9];
  const float* W1_r   = (const float*)d_in[10];
  const float* W_lin  = (const float*)d_in[11];
  const float* b_lin  = (const float*)d_in[12];
  const float* W_lin2 = (const float*)d_in[13];
  const float* b_lin2 = (const float*)d_in[14];
  float* out = (float*)d_out;

  const int N = in_sizes[0] / 64;           // 50000
  const int E = in_sizes[1] / 2;            // 800000
  const int Npad = ((N + 127) / 128) * 128; // 50048
  const int nblkM = Npad / 128;
  const int NB = (N + 63) / 64;             // 782 buckets
  const int G  = 256;                       // partition blocks (1 per CU)
  const int CH = (E + G - 1) / G;           // 3125 edges/block
  const int* e_src = ei;
  const int* e_tgt = ei + E;

  size_t off = 0;
  char* base = (char*)d_ws;
  auto carve = [&](size_t bytes) -> void* {
    void* p = base + off;
    off += (bytes + 255) & ~(size_t)255;
    return p;
  };
  int*      row_ptr = (int*)carve((size_t)(N + 1) * 4);
  int*      bcnt    = (int*)carve((size_t)NB * 4);
  int*      boff    = (int*)carve((size_t)(NB + 1) * 4);
  int*      histT   = (int*)carve((size_t)NB * G * 4);
  unsigned* vals    = (unsigned*)carve((size_t)E * 4);
  int*      srcs    = (int*)carve((size_t)(E + 16) * 4);
  unsigned short* xb    = (unsigned short*)carve((size_t)Npad * 64 * 2);
  unsigned short* mb    = (unsigned short*)carve((size_t)Npad * 64 * 2);
  unsigned short* h1b   = (unsigned short*)carve((size_t)Npad * 256 * 2);
  unsigned short* h2b   = (unsigned short*)carve((size_t)Npad * 128 * 2);
  unsigned short* yb    = (unsigned short*)carve((size_t)Npad * 128 * 2);
  unsigned short* zb    = (unsigned short*)carve((size_t)Npad * 128 * 2);
  unsigned short* Wt1hi = (unsigned short*)carve(256 * 128 * 2);
  unsigned short* Wt2hi = (unsigned short*)carve(256 * 256 * 2);
  unsigned short* Wt3hi = (unsigned short*)carve(256 * 128 * 2);
  float* Wcomb = (float*)carve(1024 * 4);
  float* bcomb = (float*)carve(8 * 4);
  (void)ws_size; (void)n_in; (void)out_size;

  const int nbConv = (N * 16 + 255) / 256;  // 3125
  const int nbPrep = nbConv + 128 + 256 + 128 + 4;
  const size_t ldsNB = (size_t)NB * 4;

  // CSR build: radix partition (no global atomics) + per-bucket sort (+prep merged)
  hist_k<<<G, 256, ldsNB, stream>>>(e_tgt, histT, E, NB, CH);
  scanb_k<<<(NB + 3) / 4, 256, 0, stream>>>(histT, bcnt, NB);
  bscan_k<<<1, 1024, 0, stream>>>(bcnt, boff, row_ptr, srcs, NB, E, N);
  scatter_k<<<G, 256, ldsNB, stream>>>(e_src, e_tgt, boff, histT, vals, E, NB, CH);
  bsort_prep_k<<<NB + nbPrep, 256, 0, stream>>>(
      vals, boff, row_ptr, srcs, N, NB,
      x, xb, nbConv, N * 16,
      Wf_l, Wf_r, Wt1hi,
      W0_l, W0_r, Wt2hi,
      W1_l, W1_r, Wt3hi,
      W_lin, b_lin, W_lin2, b_lin2, Wcomb, bcomb);

  const int nbAgg = (N + 3) / 4;
  const dim3 gemmGrid(nblkM, 2);

  // Layer 1: hi-only W (2 segs); agg64 gathers bf16 xb
  agg_mean64_k<<<nbAgg, 256, 0, stream>>>(xb, row_ptr, srcs, mb, N);
  {
    Segs s;
    s.n = 2;
    s.s[0] = {mb, Wt1hi,      64, 128, 64};
    s.s[1] = {xb, Wt1hi + 64, 64, 128, 64};
    s.s[2] = {nullptr, nullptr, 0, 0, 0};
    s.s[3] = {nullptr, nullptr, 0, 0, 0};
    gemm_mfma_k<1><<<gemmGrid, 256, 0, stream>>>(s, bf, nullptr, nullptr, h1b, 256);
  }

  // Layer 2: Y|Z fp16
  {
    Segs s;
    s.n = 1;
    s.s[0] = {h1b, Wt2hi, 256, 256, 256};
    s.s[1] = {nullptr, nullptr, 0, 0, 0};
    s.s[2] = {nullptr, nullptr, 0, 0, 0};
    s.s[3] = {nullptr, nullptr, 0, 0, 0};
    gemm_mfma_k<0><<<gemmGrid, 256, 0, stream>>>(s, nullptr, yb, zb, nullptr, 256);
  }
  agg128_k<1><<<nbAgg, 256, 0, stream>>>(yb, zb, b0, row_ptr, srcs, h2b, nullptr, nullptr, N);

  // Layer 3 + fused head
  {
    Segs s;
    s.n = 1;
    s.s[0] = {h2b, Wt3hi, 128, 128, 128};
    s.s[1] = {nullptr, nullptr, 0, 0, 0};
    s.s[2] = {nullptr, nullptr, 0, 0, 0};
    s.s[3] = {nullptr, nullptr, 0, 0, 0};
    gemm_mfma_k<0><<<gemmGrid, 256, 0, stream>>>(s, nullptr, yb, zb, nullptr, 256);
  }
  agg128_k<2><<<nbAgg, 256, 0, stream>>>(yb, zb, b1, row_ptr, srcs, out, Wcomb, bcomb, N);
}